// Round 7
// baseline (189.503 us; speedup 1.0000x reference)
//
#include <hip/hip_runtime.h>
#include <math.h>

#define D_INNER 5120
#define DT_RANK 160
#define N_STATE 16
#define BATCH   256
#define KTOT    192               // 160 (dt_low) | 16 (B) | 16 (C)

// ---- K1 config: 256-thr blocks, 4 waves x 40-dd chunks, intra-block reduce ----
#define BGRP    8                 // batches per block
#define NBG     (BATCH / BGRP)    // 32
#define DDBLK   160               // dd per block (4 waves x 40)
#define NDDB    (D_INNER / DDBLK) // 32 -> SPLIT partials
#define SPLIT   32

// ---- K3 config: FUSED, 4 batches/block, grid (20,64)=1280 blocks ----
#define K3_BT   4

// ---- workspace layout (float offsets) ----
#define OFF_T     0
#define SZ_T      (BATCH * KTOT)                  // 49,152
#define OFF_P     (OFF_T + SZ_T)
#define SZ_P      (SPLIT * BATCH * KTOT)          // 1,572,864 (6.3 MB)
#define OFF_SBC   (OFF_P + SZ_P)                  // sbc[b] = sum_n T[b][160+n]*T[b][176+n]

// ---------------------------------------------------------------------------
// K1: projection GEMM partials (unchanged, ~10 us).
// ---------------------------------------------------------------------------
__global__ __launch_bounds__(256) void k1_gemm(const float* __restrict__ x,
                                               const float* __restrict__ Wdtlow,
                                               const float* __restrict__ WB,
                                               const float* __restrict__ WC,
                                               float* __restrict__ ws) {
    __shared__ float lds[4 * BGRP * KTOT];   // 6144 floats = 24 KB
    const int tid  = threadIdx.x;
    const int lane = tid & 63;
    const int wv   = tid >> 6;               // wave 0..3
    const int b0   = blockIdx.x * BGRP;
    const int ddB  = blockIdx.y * DDBLK;

    float* xs = lds;
    for (int j = tid; j < (BGRP * DDBLK) / 4; j += 256) {   // 320 float4
        int i  = j / (DDBLK / 4);
        int c4 = j % (DDBLK / 4);
        float4 v = *(const float4*)(x + (size_t)(b0 + i) * D_INNER + ddB + c4 * 4);
        *(float4*)(xs + i * DDBLK + c4 * 4) = v;
    }
    __syncthreads();

    const int dd0 = wv * 40;
    const float* p0 = Wdtlow + (size_t)(ddB + dd0) * DT_RANK + lane;
    const float* p1 = p0 + 64;
    const float* p2;
    int st2;
    if (lane < 32)      { p2 = p0 + 128;                                          st2 = DT_RANK; }
    else if (lane < 48) { p2 = WB + (size_t)(ddB + dd0) * N_STATE + (lane - 32);  st2 = N_STATE; }
    else                { p2 = WC + (size_t)(ddB + dd0) * N_STATE + (lane - 48);  st2 = N_STATE; }

    float acc0[BGRP], acc1[BGRP], acc2[BGRP];
#pragma unroll
    for (int i = 0; i < BGRP; ++i) { acc0[i] = 0.f; acc1[i] = 0.f; acc2[i] = 0.f; }

#pragma unroll 2
    for (int g = 0; g < 10; ++g) {           // 4 dd per group
        float w0[4], w1[4], w2[4];
#pragma unroll
        for (int u = 0; u < 4; ++u) {
            int dd = g * 4 + u;
            w0[u] = p0[(size_t)dd * DT_RANK];
            w1[u] = p1[(size_t)dd * DT_RANK];
            w2[u] = p2[(size_t)dd * st2];
        }
#pragma unroll
        for (int i = 0; i < BGRP; ++i) {
            float4 xv = *(const float4*)(xs + i * DDBLK + dd0 + g * 4);
            acc0[i] += xv.x * w0[0] + xv.y * w0[1] + xv.z * w0[2] + xv.w * w0[3];
            acc1[i] += xv.x * w1[0] + xv.y * w1[1] + xv.z * w1[2] + xv.w * w1[3];
            acc2[i] += xv.x * w2[0] + xv.y * w2[1] + xv.z * w2[2] + xv.w * w2[3];
        }
    }
    __syncthreads();

#pragma unroll
    for (int i = 0; i < BGRP; ++i) {
        float* r = lds + wv * (BGRP * KTOT) + i * KTOT;
        r[lane]       = acc0[i];
        r[lane + 64]  = acc1[i];
        r[lane + 128] = acc2[i];
    }
    __syncthreads();

    float* P = ws + OFF_P + (size_t)blockIdx.y * (BATCH * KTOT) + (size_t)b0 * KTOT;
#pragma unroll
    for (int r = 0; r < 6; ++r) {
        int idx = tid + r * 256;
        P[idx] = lds[idx] + lds[idx + 1536] + lds[idx + 3072] + lds[idx + 4608];
    }
}

// ---------------------------------------------------------------------------
// K2: reduce split-K partials -> T[256][192], plus hoisted sbc[b]. (unchanged)
// ---------------------------------------------------------------------------
__global__ __launch_bounds__(192) void k2_reduce(float* __restrict__ ws) {
    __shared__ float ts[KTOT];
    const int b   = blockIdx.x;
    const int col = threadIdx.x;
    const float* P = ws + OFF_P + (size_t)b * KTOT + col;
    float a = 0.f;
#pragma unroll
    for (int s = 0; s < SPLIT; ++s) a += P[(size_t)s * (BATCH * KTOT)];
    ws[OFF_T + b * KTOT + col] = a;
    ts[col] = a;
    __syncthreads();
    if (col == 0) {
        float s2 = 0.f;
#pragma unroll
        for (int n = 0; n < N_STATE; ++n) s2 += ts[160 + n] * ts[176 + n];
        ws[OFF_SBC + b] = s2;
    }
}

// ---------------------------------------------------------------------------
// K3: FUSED delta GEMM + softplus + scan — SCHEDULE-ENFORCEMENT round.
// Diagnosis: rounds 5/6 VGPR_Count=56/40 prove the compiler SINKS every
// issue-early prefetch (can't hold 32+ regs of h0 in a 40-VGPR kernel).
// The emitted GEMM is group-serial {8 loads -> vmcnt(0) -> FMA} with ~250cy
// exposed L2 latency x20, and the scan eats h0 latency cold -> K3 pinned at
// 41-52us regardless of occupancy (34% vs 52% identical time).
// Enforcement:
//  (1) sched_barrier(0) after the h0(b0,b1)/x/A issue block: loads CANNOT
//      be sunk below it. Verification marker: VGPR_Count >= ~80.
//  (2) Explicit double-buffered GEMM (wA/wB, 8-deep, rotation loop with
//      peeled prologue/epilogue, no OOB): each half-step issues 8 loads and
//      consumes the OTHER buffer -> counted vmcnt (never-drain), L2 latency
//      overlapped with FMAs. k-ascending order preserved -> bit-identical.
//  (3) Scan prefetches batches 2,3 one iteration ahead, each pinned by its
//      own sched_barrier(0).
// Structure/occupancy: BT=4, grid (20,64)=1280 (round-4 best, K3~41.5us);
// __launch_bounds__(256,5) cap 102 VGPR, need ~90. 5 blocks/CU x 4 waves.
// ---------------------------------------------------------------------------
__global__ __launch_bounds__(256, 5) void k3_fused(const float* __restrict__ Wdt,
                                                   const float* __restrict__ b_dt,
                                                   const float* __restrict__ x,
                                                   const float* __restrict__ A,
                                                   const float* __restrict__ Dv,
                                                   const float* __restrict__ h0,
                                                   const float* __restrict__ ws,
                                                   float* __restrict__ out) {
    const int tid = threadIdx.x;
    const int d   = blockIdx.x * 256 + tid;
    const int b0  = blockIdx.y * K3_BT;
    const float* T  = ws + OFF_T;
    const float* SB = ws + OFF_SBC;

    // ---- issue long-latency loads: h0 batches 0,1 + x[0..3] + A + consts ----
    const float4* hb = (const float4*)(h0 + ((size_t)b0 * D_INNER + d) * N_STATE);
    const size_t  hstride = (size_t)D_INNER * 4;     // float4s per batch step

    float4 hA0 = hb[0],           hA1 = hb[1],           hA2 = hb[2],           hA3 = hb[3];
    float4 hB0 = hb[hstride + 0], hB1 = hb[hstride + 1], hB2 = hb[hstride + 2], hB3 = hb[hstride + 3];

    float xv[K3_BT];
#pragma unroll
    for (int i = 0; i < K3_BT; ++i) xv[i] = x[(size_t)(b0 + i) * D_INNER + d];

    const float4* a4 = (const float4*)(A + (size_t)d * N_STATE);
    float4 a0 = a4[0], a1 = a4[1], a2 = a4[2], a3 = a4[3];
    const float bdt = b_dt[d];
    const float Dd  = Dv[d];

    // FENCE: nothing above may sink below this point (prefetch is mandatory).
    __builtin_amdgcn_sched_barrier(0);

    // ---- delta GEMM, explicitly double-buffered over k (8-deep x 2) ----
    // acc[i] = T[b0+i][0..159] . Wdt[:,d]; T rows wave-uniform -> s_loads.
    const float* wp = Wdt + d;
    const float* tA = T + (size_t)b0 * KTOT;
    const float* tB = tA + KTOT;
    const float* tC = tB + KTOT;
    const float* tD = tC + KTOT;

    float acc0 = 0.f, acc1 = 0.f, acc2 = 0.f, acc3 = 0.f;
    float wA[8], wB[8];

#pragma unroll
    for (int u = 0; u < 8; ++u) wA[u] = wp[(size_t)u * D_INNER];     // k=0..7

#define FMA8(TBUF, KOFF)                                                      \
    _Pragma("unroll")                                                         \
    for (int u = 0; u < 8; ++u) {                                             \
        float w = TBUF[u];                                                    \
        int   k = (KOFF) + u;                                                 \
        acc0 += tA[k] * w;  acc1 += tB[k] * w;                                \
        acc2 += tC[k] * w;  acc3 += tD[k] * w;                                \
    }

#pragma unroll 1
    for (int g = 0; g < 9; ++g) {            // k = 0..143 consumed here
        const int k0 = g * 16;
#pragma unroll
        for (int u = 0; u < 8; ++u) wB[u] = wp[(size_t)(k0 + 8 + u) * D_INNER];
        FMA8(wA, k0)                          // consume wA while wB in flight
#pragma unroll
        for (int u = 0; u < 8; ++u) wA[u] = wp[(size_t)(k0 + 16 + u) * D_INNER];
        FMA8(wB, k0 + 8)                      // consume wB while wA in flight
    }
    // epilogue: k = 144..159 (wA holds k=144..151; no OOB loads issued)
#pragma unroll
    for (int u = 0; u < 8; ++u) wB[u] = wp[(size_t)(152 + u) * D_INNER];
    FMA8(wA, 144)
    FMA8(wB, 152)
#undef FMA8

    // ---- scan over 4 batches; batches 2,3 prefetched one iter ahead ----
#define SCAN_BODY(ACC, XV, BIDX, TB, H0, H1, H2, H3)                          \
    {                                                                         \
        float v     = (ACC) + bdt;                                            \
        float delta = (v > 20.f) ? v : log1pf(__expf(v));                     \
        float sbc   = SB[BIDX];                                               \
        float y0, y1, y2, y3;                                                 \
        y0  = __expf(delta * a0.x) * H0.x * (TB)[176 + 0];                    \
        y0 += __expf(delta * a0.y) * H0.y * (TB)[176 + 1];                    \
        y0 += __expf(delta * a0.z) * H0.z * (TB)[176 + 2];                    \
        y0 += __expf(delta * a0.w) * H0.w * (TB)[176 + 3];                    \
        y1  = __expf(delta * a1.x) * H1.x * (TB)[176 + 4];                    \
        y1 += __expf(delta * a1.y) * H1.y * (TB)[176 + 5];                    \
        y1 += __expf(delta * a1.z) * H1.z * (TB)[176 + 6];                    \
        y1 += __expf(delta * a1.w) * H1.w * (TB)[176 + 7];                    \
        y2  = __expf(delta * a2.x) * H2.x * (TB)[176 + 8];                    \
        y2 += __expf(delta * a2.y) * H2.y * (TB)[176 + 9];                    \
        y2 += __expf(delta * a2.z) * H2.z * (TB)[176 + 10];                   \
        y2 += __expf(delta * a2.w) * H2.w * (TB)[176 + 11];                   \
        y3  = __expf(delta * a3.x) * H3.x * (TB)[176 + 12];                   \
        y3 += __expf(delta * a3.y) * H3.y * (TB)[176 + 13];                   \
        y3 += __expf(delta * a3.z) * H3.z * (TB)[176 + 14];                   \
        y3 += __expf(delta * a3.w) * H3.w * (TB)[176 + 15];                   \
        out[(size_t)(BIDX) * D_INNER + d] = (XV) * (Dd + delta * sbc)         \
                                          + ((y0 + y1) + (y2 + y3));          \
    }

    // iter 0: issue batch-2 h0, pin, compute batch 0
    const float4* hpC = hb + 2 * hstride;
    float4 hC0 = hpC[0], hC1 = hpC[1], hC2 = hpC[2], hC3 = hpC[3];
    __builtin_amdgcn_sched_barrier(0);
    SCAN_BODY(acc0, xv[0], b0 + 0, tA, hA0, hA1, hA2, hA3)

    // iter 1: issue batch-3 h0, pin, compute batch 1
    const float4* hpD = hb + 3 * hstride;
    float4 hD0 = hpD[0], hD1 = hpD[1], hD2 = hpD[2], hD3 = hpD[3];
    __builtin_amdgcn_sched_barrier(0);
    SCAN_BODY(acc1, xv[1], b0 + 1, tB, hB0, hB1, hB2, hB3)

    // iters 2,3: data already in flight/registers
    SCAN_BODY(acc2, xv[2], b0 + 2, tC, hC0, hC1, hC2, hC3)
    SCAN_BODY(acc3, xv[3], b0 + 3, tD, hD0, hD1, hD2, hD3)
#undef SCAN_BODY
}

// ---------------------------------------------------------------------------
extern "C" void kernel_launch(void* const* d_in, const int* in_sizes, int n_in,
                              void* d_out, int out_size, void* d_ws, size_t ws_size,
                              hipStream_t stream) {
    const float* x      = (const float*)d_in[0];
    const float* Wdtlow = (const float*)d_in[1];
    const float* Wdt    = (const float*)d_in[2];
    const float* bdt    = (const float*)d_in[3];
    const float* WB     = (const float*)d_in[4];
    const float* WC     = (const float*)d_in[5];
    const float* A      = (const float*)d_in[6];
    const float* Dv     = (const float*)d_in[7];
    const float* h0     = (const float*)d_in[8];
    float* ws  = (float*)d_ws;
    float* out = (float*)d_out;

    // K1: projection GEMM partials (1024 blocks, unchanged)
    hipLaunchKernelGGL(k1_gemm, dim3(NBG, NDDB), dim3(256), 0, stream,
                       x, Wdtlow, WB, WC, ws);
    // K2: reduce partials -> T[256][192] + sbc[256]
    hipLaunchKernelGGL(k2_reduce, dim3(BATCH), dim3(192), 0, stream, ws);
    // K3: fused delta GEMM + scan, BT=4, grid (20,64)=1280 blocks
    hipLaunchKernelGGL(k3_fused, dim3(D_INNER / 256, BATCH / K3_BT), dim3(256),
                       0, stream, Wdt, bdt, x, A, Dv, h0, ws, out);
}

// Round 8
// 175.665 us; speedup vs baseline: 1.0788x; 1.0788x over previous
//
#include <hip/hip_runtime.h>
#include <math.h>

#define D_INNER 5120
#define DT_RANK 160
#define N_STATE 16
#define BATCH   256
#define KTOT    192               // 160 (dt_low) | 16 (B) | 16 (C)

// ---- K1 config: 256-thr blocks, 4 waves x 40-dd chunks, intra-block reduce ----
#define BGRP    8                 // batches per block
#define NBG     (BATCH / BGRP)    // 32
#define DDBLK   160               // dd per block (4 waves x 40)
#define NDDB    (D_INNER / DDBLK) // 32 -> SPLIT partials
#define SPLIT   32

// ---- K3 config: FUSED, 4 batches/block, grid (20,64)=1280 blocks ----
#define K3_BT   4
#define KC      16                // k-rows per staged Wdt chunk (16 KB)
#define NCHUNK  (DT_RANK / KC)    // 10

// ---- workspace layout (float offsets) ----
#define OFF_T     0
#define SZ_T      (BATCH * KTOT)                  // 49,152
#define OFF_P     (OFF_T + SZ_T)
#define SZ_P      (SPLIT * BATCH * KTOT)          // 1,572,864 (6.3 MB)
#define OFF_SBC   (OFF_P + SZ_P)                  // sbc[b] = sum_n T[b][160+n]*T[b][176+n]

// ---------------------------------------------------------------------------
// K1: projection GEMM partials (unchanged, ~10 us).
// ---------------------------------------------------------------------------
__global__ __launch_bounds__(256) void k1_gemm(const float* __restrict__ x,
                                               const float* __restrict__ Wdtlow,
                                               const float* __restrict__ WB,
                                               const float* __restrict__ WC,
                                               float* __restrict__ ws) {
    __shared__ float lds[4 * BGRP * KTOT];   // 6144 floats = 24 KB
    const int tid  = threadIdx.x;
    const int lane = tid & 63;
    const int wv   = tid >> 6;               // wave 0..3
    const int b0   = blockIdx.x * BGRP;
    const int ddB  = blockIdx.y * DDBLK;

    float* xs = lds;
    for (int j = tid; j < (BGRP * DDBLK) / 4; j += 256) {   // 320 float4
        int i  = j / (DDBLK / 4);
        int c4 = j % (DDBLK / 4);
        float4 v = *(const float4*)(x + (size_t)(b0 + i) * D_INNER + ddB + c4 * 4);
        *(float4*)(xs + i * DDBLK + c4 * 4) = v;
    }
    __syncthreads();

    const int dd0 = wv * 40;
    const float* p0 = Wdtlow + (size_t)(ddB + dd0) * DT_RANK + lane;
    const float* p1 = p0 + 64;
    const float* p2;
    int st2;
    if (lane < 32)      { p2 = p0 + 128;                                          st2 = DT_RANK; }
    else if (lane < 48) { p2 = WB + (size_t)(ddB + dd0) * N_STATE + (lane - 32);  st2 = N_STATE; }
    else                { p2 = WC + (size_t)(ddB + dd0) * N_STATE + (lane - 48);  st2 = N_STATE; }

    float acc0[BGRP], acc1[BGRP], acc2[BGRP];
#pragma unroll
    for (int i = 0; i < BGRP; ++i) { acc0[i] = 0.f; acc1[i] = 0.f; acc2[i] = 0.f; }

#pragma unroll 2
    for (int g = 0; g < 10; ++g) {           // 4 dd per group
        float w0[4], w1[4], w2[4];
#pragma unroll
        for (int u = 0; u < 4; ++u) {
            int dd = g * 4 + u;
            w0[u] = p0[(size_t)dd * DT_RANK];
            w1[u] = p1[(size_t)dd * DT_RANK];
            w2[u] = p2[(size_t)dd * st2];
        }
#pragma unroll
        for (int i = 0; i < BGRP; ++i) {
            float4 xv = *(const float4*)(xs + i * DDBLK + dd0 + g * 4);
            acc0[i] += xv.x * w0[0] + xv.y * w0[1] + xv.z * w0[2] + xv.w * w0[3];
            acc1[i] += xv.x * w1[0] + xv.y * w1[1] + xv.z * w1[2] + xv.w * w1[3];
            acc2[i] += xv.x * w2[0] + xv.y * w2[1] + xv.z * w2[2] + xv.w * w2[3];
        }
    }
    __syncthreads();

#pragma unroll
    for (int i = 0; i < BGRP; ++i) {
        float* r = lds + wv * (BGRP * KTOT) + i * KTOT;
        r[lane]       = acc0[i];
        r[lane + 64]  = acc1[i];
        r[lane + 128] = acc2[i];
    }
    __syncthreads();

    float* P = ws + OFF_P + (size_t)blockIdx.y * (BATCH * KTOT) + (size_t)b0 * KTOT;
#pragma unroll
    for (int r = 0; r < 6; ++r) {
        int idx = tid + r * 256;
        P[idx] = lds[idx] + lds[idx + 1536] + lds[idx + 3072] + lds[idx + 4608];
    }
}

// ---------------------------------------------------------------------------
// K2: reduce split-K partials -> T[256][192], plus hoisted sbc[b]. (unchanged)
// ---------------------------------------------------------------------------
__global__ __launch_bounds__(192) void k2_reduce(float* __restrict__ ws) {
    __shared__ float ts[KTOT];
    const int b   = blockIdx.x;
    const int col = threadIdx.x;
    const float* P = ws + OFF_P + (size_t)b * KTOT + col;
    float a = 0.f;
#pragma unroll
    for (int s = 0; s < SPLIT; ++s) a += P[(size_t)s * (BATCH * KTOT)];
    ws[OFF_T + b * KTOT + col] = a;
    ts[col] = a;
    __syncthreads();
    if (col == 0) {
        float s2 = 0.f;
#pragma unroll
        for (int n = 0; n < N_STATE; ++n) s2 += ts[160 + n] * ts[176 + n];
        ws[OFF_SBC + b] = s2;
    }
}

// ---------------------------------------------------------------------------
// K3: FUSED delta GEMM + softplus + scan — global_load_lds STAGING round.
// Proven across r5/r6/r7 (VGPR 56/40/48 + r7 spill traffic): the compiler
// will NOT hold deep per-thread VGPR prefetches — it sinks them or spills.
// global_load_lds sidesteps that failure mode entirely: the staging loads
// consume ZERO VGPRs (async DMA global->LDS), so nothing can be sunk/spilled.
// GEMM: Wdt staged in 16-k-row chunks (16KB), double-buffered (32KB/block ->
// exactly 5 blocks/CU = the grid's residency). 2-phase loop (T3-minimum):
//   region c: STAGE(c+1) -> compute(c from other buf) -> __syncthreads()
// The stage's ~200cy L2 latency is covered by the 16 ds_read + 64 FMA of
// compute(c); the per-8-load exposed-latency cadence of rounds 0-7 is gone.
// ds_read lds[k*256+tid]: consecutive lanes -> consecutive banks, no
// conflicts. k-ascending accumulation preserved -> bit-identical numerics.
// Scan: round-4 verbatim (best measured). No sched_barriers (r7 lesson).
// ---------------------------------------------------------------------------
__global__ __launch_bounds__(256, 5) void k3_fused(const float* __restrict__ Wdt,
                                                   const float* __restrict__ b_dt,
                                                   const float* __restrict__ x,
                                                   const float* __restrict__ A,
                                                   const float* __restrict__ Dv,
                                                   const float* __restrict__ h0,
                                                   const float* __restrict__ ws,
                                                   float* __restrict__ out) {
    __shared__ float ldsA[KC * 256];   // 16 KB
    __shared__ float ldsB[KC * 256];   // 16 KB
    const int tid  = threadIdx.x;
    const int lane = tid & 63;
    const int wv4  = (tid >> 6) * 4;            // this wave's 4 staged rows
    const int dblk = blockIdx.x * 256;
    const int d    = dblk + tid;
    const int b0   = blockIdx.y * K3_BT;
    const float* T  = ws + OFF_T;
    const float* SB = ws + OFF_SBC;

    // ---- issue h0 batches 0,1 + x early (round-4 shape; sinking tolerated) ----
    const float4* hb = (const float4*)(h0 + ((size_t)b0 * D_INNER + d) * N_STATE);
    const size_t  hstride = (size_t)D_INNER * 4;     // float4s per batch step

    float4 hc0 = hb[0], hc1 = hb[1], hc2 = hb[2], hc3 = hb[3];
    const float4* h1p = hb + hstride;
    float4 hn0 = h1p[0], hn1 = h1p[1], hn2 = h1p[2], hn3 = h1p[3];

    float xv[K3_BT];
#pragma unroll
    for (int i = 0; i < K3_BT; ++i) xv[i] = x[(size_t)(b0 + i) * D_INNER + d];

    const float bdt = b_dt[d];
    const float Dd  = Dv[d];
    const float4* a4 = (const float4*)(A + (size_t)d * N_STATE);
    float4 a0 = a4[0], a1 = a4[1], a2 = a4[2], a3 = a4[3];

    // ---- Wdt chunk staging: wave wv stages rows wv*4+u of the chunk ----
    // LDS dest is wave-uniform base + lane*16B (HW rule); global src is
    // per-lane. Result: buf[r*256 + c] = Wdt[kc+r][dblk + c].
#define STAGE(KC0, DSTBUF)                                                    \
    {                                                                         \
        _Pragma("unroll")                                                     \
        for (int u = 0; u < 4; ++u) {                                         \
            const int r = wv4 + u;                                            \
            const float* s = Wdt + (size_t)((KC0) + r) * D_INNER              \
                           + dblk + lane * 4;                                 \
            __builtin_amdgcn_global_load_lds(                                 \
                (const __attribute__((address_space(1))) void*)s,             \
                (__attribute__((address_space(3))) void*)((DSTBUF) + r * 256),\
                16, 0, 0);                                                    \
        }                                                                     \
    }

    // ---- delta GEMM: acc[i] = T[b0+i][0..159] . Wdt[:,d], LDS-staged ----
    const float* tA = T + (size_t)b0 * KTOT;    // wave-uniform -> s_loads
    const float* tB = tA + KTOT;
    const float* tC = tB + KTOT;
    const float* tD = tC + KTOT;

    float acc0 = 0.f, acc1 = 0.f, acc2 = 0.f, acc3 = 0.f;

    STAGE(0, ldsA)
    __syncthreads();                            // chunk 0 landed

#pragma unroll 1
    for (int c = 0; c < NCHUNK; ++c) {
        if (c < NCHUNK - 1) STAGE((c + 1) * KC, (c & 1) ? ldsA : ldsB)
        const float* cb = (c & 1) ? ldsB : ldsA;
        const int kbase = c * KC;
#pragma unroll
        for (int kk = 0; kk < KC; ++kk) {
            float w = cb[kk * 256 + tid];
            int   k = kbase + kk;
            acc0 += tA[k] * w;
            acc1 += tB[k] * w;
            acc2 += tC[k] * w;
            acc3 += tD[k] * w;
        }
        __syncthreads();                        // next chunk landed, reads done
    }
#undef STAGE

    float accv[K3_BT] = {acc0, acc1, acc2, acc3};

    // ---- scan over 4 batches, 2-deep h0 prefetch (round-4 verbatim) ----
#pragma unroll
    for (int i = 0; i < K3_BT; ++i) {
        float4 p0, p1, p2, p3;
        if (i + 2 < K3_BT) {                          // prefetch batch i+2
            const float4* hp = hb + (size_t)(i + 2) * hstride;
            p0 = hp[0]; p1 = hp[1]; p2 = hp[2]; p3 = hp[3];
        }

        const int b = b0 + i;
        const float* Tb = T + (size_t)b * KTOT;       // uniform -> s_loads

        float v     = accv[i] + bdt;
        float delta = (v > 20.f) ? v : log1pf(__expf(v));
        float sbc   = SB[b];                          // hoisted to K2

        float y0, y1, y2, y3;                         // 4 partials: short chains
        y0  = __expf(delta * a0.x) * hc0.x * Tb[176 + 0];
        y0 += __expf(delta * a0.y) * hc0.y * Tb[176 + 1];
        y0 += __expf(delta * a0.z) * hc0.z * Tb[176 + 2];
        y0 += __expf(delta * a0.w) * hc0.w * Tb[176 + 3];
        y1  = __expf(delta * a1.x) * hc1.x * Tb[176 + 4];
        y1 += __expf(delta * a1.y) * hc1.y * Tb[176 + 5];
        y1 += __expf(delta * a1.z) * hc1.z * Tb[176 + 6];
        y1 += __expf(delta * a1.w) * hc1.w * Tb[176 + 7];
        y2  = __expf(delta * a2.x) * hc2.x * Tb[176 + 8];
        y2 += __expf(delta * a2.y) * hc2.y * Tb[176 + 9];
        y2 += __expf(delta * a2.z) * hc2.z * Tb[176 + 10];
        y2 += __expf(delta * a2.w) * hc2.w * Tb[176 + 11];
        y3  = __expf(delta * a3.x) * hc3.x * Tb[176 + 12];
        y3 += __expf(delta * a3.y) * hc3.y * Tb[176 + 13];
        y3 += __expf(delta * a3.z) * hc3.z * Tb[176 + 14];
        y3 += __expf(delta * a3.w) * hc3.w * Tb[176 + 15];

        out[(size_t)b * D_INNER + d] = xv[i] * (Dd + delta * sbc)
                                     + ((y0 + y1) + (y2 + y3));

        if (i < K3_BT - 1) { hc0 = hn0; hc1 = hn1; hc2 = hn2; hc3 = hn3; }
        if (i + 2 < K3_BT) { hn0 = p0;  hn1 = p1;  hn2 = p2;  hn3 = p3;  }
    }
}

// ---------------------------------------------------------------------------
extern "C" void kernel_launch(void* const* d_in, const int* in_sizes, int n_in,
                              void* d_out, int out_size, void* d_ws, size_t ws_size,
                              hipStream_t stream) {
    const float* x      = (const float*)d_in[0];
    const float* Wdtlow = (const float*)d_in[1];
    const float* Wdt    = (const float*)d_in[2];
    const float* bdt    = (const float*)d_in[3];
    const float* WB     = (const float*)d_in[4];
    const float* WC     = (const float*)d_in[5];
    const float* A      = (const float*)d_in[6];
    const float* Dv     = (const float*)d_in[7];
    const float* h0     = (const float*)d_in[8];
    float* ws  = (float*)d_ws;
    float* out = (float*)d_out;

    // K1: projection GEMM partials (1024 blocks, unchanged)
    hipLaunchKernelGGL(k1_gemm, dim3(NBG, NDDB), dim3(256), 0, stream,
                       x, Wdtlow, WB, WC, ws);
    // K2: reduce partials -> T[256][192] + sbc[256]
    hipLaunchKernelGGL(k2_reduce, dim3(BATCH), dim3(192), 0, stream, ws);
    // K3: fused delta GEMM (LDS-staged Wdt) + scan, BT=4, grid (20,64)
    hipLaunchKernelGGL(k3_fused, dim3(D_INNER / 256, BATCH / K3_BT), dim3(256),
                       0, stream, Wdt, bdt, x, A, Dv, h0, ws, out);
}